// Round 2
// baseline (719.836 us; speedup 1.0000x reference)
//
#include <hip/hip_runtime.h>
#include <stdint.h>

// Problem constants: x[16,64,256,256] fp32, W[1024,1024] fp32, P=4.
// GEMM view: C[m,n] = sum_k A[m,k] * W[n,k]
//   m = b*4096 + hp*64 + wp   (Hp=Wp=64)
//   k = c*16 + ph*4 + pw
// Tiling: BM=128 (2 hp-rows x 64 wp), BN=128, BK=32 (2 channels), 32 K-iters.
//
// Round-2 structure: A bypasses LDS entirely (fragments load straight from
// global: per lane the 8 k-values are two contiguous float4s, coalesced
// across each 16-lane group). B double-buffers in LDS. One raw s_barrier
// per iteration with lgkmcnt-only drain -> global prefetches (A it+1,
// B it+2) stay in flight across the barrier.

typedef float    f32x4  __attribute__((ext_vector_type(4)));
typedef uint32_t u32x4  __attribute__((ext_vector_type(4)));
typedef __bf16   bf16x8 __attribute__((ext_vector_type(8)));

// Truncate two f32 to bf16 and pack into one u32 (lo in low half).
__device__ __forceinline__ uint32_t pack2(float lo, float hi) {
    return __builtin_amdgcn_perm(__builtin_bit_cast(uint32_t, hi),
                                 __builtin_bit_cast(uint32_t, lo),
                                 0x07060302u);
}

__global__ __launch_bounds__(256, 3)
void patchmix_kernel(const float* __restrict__ x,
                     const float* __restrict__ Wm,
                     float* __restrict__ y) {
    // ---- XCD-aware block swizzle (T1): contiguous M-chunk per XCD, N fastest.
    const int bx  = blockIdx.x;
    const int xcd = bx & 7;
    const int jj  = bx >> 3;       // 0..511 within this XCD
    const int nt  = jj & 7;        // N-tile fastest -> A-strip L2 reuse
    const int mt  = xcd * 64 + (jj >> 3);   // 0..511
    const int bb  = mt >> 5;       // batch 0..15
    const int hp0 = (mt & 31) << 1;// first of 2 hp rows
    const int n0  = nt << 7;

    const int t    = threadIdx.x;
    const int lane = t & 63;
    const int wave = t >> 6;
    const int wm   = wave >> 1;    // wave row in 2x2 grid
    const int wn   = wave & 1;     // wave col

    // B tile only, double-buffered: [buf][kq(0..3)][rowS(0..127)] of u32x4.
    // XOR skew (row ^ (kq<<1)) keeps writes/reads bank-conflict-free.
    __shared__ u32x4 Blds[2][4 * 128];

    const int kg  = lane >> 4;   // k-group 0..3
    const int lr  = lane & 15;
    const int lrS = lr ^ (kg << 1);

    // ---- A fragment direct-load base ----
    // af[i]: lane holds A[m = wm*64 + i*16 + lr][k = kg*8 + j], j=0..7.
    // k -> (c = 2*it + (kg>>1), ph = 2*(kg&1) + (j>>2), pw = j&3):
    // two float4s at +0 and +256 floats; i steps wp by 16 -> +64 floats.
    const float* aFragBase = x + (size_t)bb * 4194304
                           + (size_t)(kg >> 1) * 65536
                           + ((size_t)(hp0 + wm) * 4 + 2 * (kg & 1)) * 256
                           + lr * 4;

    // ---- B staging geometry ----
    const int bN  = t >> 2;                  // n_local 0..63 (round0), +64 (round1)
    const int bKq = t & 3;
    const int bNs = bN ^ (bKq << 1);         // skewed row
    const float* bBase0 = Wm + (size_t)(n0 + bN) * 1024 + bKq * 8;

    f32x4 aR[4][2];   // A(it) fragments, fp32
    f32x4 bR[2][2];   // B(it+?) staging regs

    auto loadA = [&](int it) {
        const float* a = aFragBase + (size_t)it * 131072;   // 2 channels/iter
        #pragma unroll
        for (int i = 0; i < 4; ++i) {
            aR[i][0] = *(const f32x4*)(a + i * 64);
            aR[i][1] = *(const f32x4*)(a + i * 64 + 256);
        }
    };
    auto loadB = [&](int it) {
        const float* b0 = bBase0 + it * 32;
        bR[0][0] = *(const f32x4*)(b0);
        bR[0][1] = *(const f32x4*)(b0 + 4);
        bR[1][0] = *(const f32x4*)(b0 + 65536);   // +64 rows * 1024
        bR[1][1] = *(const f32x4*)(b0 + 65536 + 4);
    };

    f32x4 acc[4][4];
    #pragma unroll
    for (int i = 0; i < 4; ++i)
        #pragma unroll
        for (int j = 0; j < 4; ++j)
            acc[i][j] = (f32x4){0.f, 0.f, 0.f, 0.f};

    // ---- prologue: A(0), B(0)->LDS buf0, B(1) in regs ----
    loadA(0);
    loadB(0);
    {
        u32x4 bpk0 = (u32x4){ pack2(bR[0][0].x, bR[0][0].y), pack2(bR[0][0].z, bR[0][0].w),
                              pack2(bR[0][1].x, bR[0][1].y), pack2(bR[0][1].z, bR[0][1].w) };
        u32x4 bpk1 = (u32x4){ pack2(bR[1][0].x, bR[1][0].y), pack2(bR[1][0].z, bR[1][0].w),
                              pack2(bR[1][1].x, bR[1][1].y), pack2(bR[1][1].z, bR[1][1].w) };
        Blds[0][bKq * 128 + bNs]      = bpk0;
        Blds[0][bKq * 128 + 64 + bNs] = bpk1;
    }
    loadB(1);
    asm volatile("s_waitcnt lgkmcnt(0)" ::: "memory");
    __builtin_amdgcn_s_barrier();
    asm volatile("" ::: "memory");

    // ---- main loop: invariants at top of body(it):
    //   B(it) in bldsR; B(it+1) in bR; A(it) in aR.
    auto body = [&](int it, u32x4* bldsR, u32x4* bldsW) {
        // 1. pack A(it) -> fragments (frees aR)
        bf16x8 af[4];
        #pragma unroll
        for (int i = 0; i < 4; ++i) {
            u32x4 ap = (u32x4){ pack2(aR[i][0].x, aR[i][0].y), pack2(aR[i][0].z, aR[i][0].w),
                                pack2(aR[i][1].x, aR[i][1].y), pack2(aR[i][1].z, aR[i][1].w) };
            af[i] = __builtin_bit_cast(bf16x8, ap);
        }
        // 2. prefetch A(it+1)  (wrap: last iter loads iter-0 data, unused)
        loadA((it + 1) & 31);
        // 3. pack B(it+1) -> write into bldsW (read next iteration)
        {
            u32x4 bpk0 = (u32x4){ pack2(bR[0][0].x, bR[0][0].y), pack2(bR[0][0].z, bR[0][0].w),
                                  pack2(bR[0][1].x, bR[0][1].y), pack2(bR[0][1].z, bR[0][1].w) };
            u32x4 bpk1 = (u32x4){ pack2(bR[1][0].x, bR[1][0].y), pack2(bR[1][0].z, bR[1][0].w),
                                  pack2(bR[1][1].x, bR[1][1].y), pack2(bR[1][1].z, bR[1][1].w) };
            bldsW[bKq * 128 + bNs]      = bpk0;
            bldsW[bKq * 128 + 64 + bNs] = bpk1;
        }
        // 4. prefetch B(it+2)
        loadB((it + 2) & 31);
        // 5. read B(it) fragments
        bf16x8 bfr[4];
        #pragma unroll
        for (int j = 0; j < 4; ++j)
            bfr[j] = __builtin_bit_cast(bf16x8, bldsR[kg * 128 + wn * 64 + j * 16 + lrS]);
        // 6. MFMA
        #pragma unroll
        for (int i = 0; i < 4; ++i)
            #pragma unroll
            for (int j = 0; j < 4; ++j)
                acc[i][j] = __builtin_amdgcn_mfma_f32_16x16x32_bf16(
                                af[i], bfr[j], acc[i][j], 0, 0, 0);
        // 7. barrier: lgkm-only drain (ds_writes committed; global prefetch
        //    stays in flight -> no vmcnt(0) structural stall)
        asm volatile("s_waitcnt lgkmcnt(0)" ::: "memory");
        __builtin_amdgcn_s_barrier();
        asm volatile("" ::: "memory");
    };

    #pragma unroll 1
    for (int it2 = 0; it2 < 16; ++it2) {
        body(2 * it2,     &Blds[0][0], &Blds[1][0]);
        body(2 * it2 + 1, &Blds[1][0], &Blds[0][0]);
    }

    // ---- epilogue: fold back to y[b][c][h][w] ----
    // D layout (m89): col n = lane&15, row m = (lane>>4)*4 + reg
    // m_local = wm*64 + i*16 + kg*4 + r  ->  hpL = wm, wp = i*16 + kg*4 + r
    float* yb = y + (size_t)bb * (64 * 256 * 256)
                  + ((size_t)(hp0 + wm) * 4) * 256;
    #pragma unroll
    for (int j = 0; j < 4; ++j) {
        const int ng = n0 + wn * 64 + j * 16 + lr;   // output channel-dim index e
        const int cc = ng >> 4;
        const int ph = (ng >> 2) & 3;
        const int pw = ng & 3;
        float* ybase = yb + ((size_t)cc * 256 + ph) * 256 + pw;
        #pragma unroll
        for (int i = 0; i < 4; ++i) {
            const int wpB = i * 16 + kg * 4;
            #pragma unroll
            for (int r = 0; r < 4; ++r)
                ybase[(size_t)(wpB + r) * 4] = acc[i][j][r];
        }
    }
}

extern "C" void kernel_launch(void* const* d_in, const int* in_sizes, int n_in,
                              void* d_out, int out_size, void* d_ws, size_t ws_size,
                              hipStream_t stream) {
    (void)in_sizes; (void)n_in; (void)d_ws; (void)ws_size; (void)out_size;
    const float* x  = (const float*)d_in[0];
    const float* Wm = (const float*)d_in[1];
    float* y = (float*)d_out;
    // 512 M-tiles x 8 N-tiles, XCD-swizzled inside the kernel
    patchmix_kernel<<<dim3(4096), dim3(256), 0, stream>>>(x, Wm, y);
}

// Round 3
// 666.230 us; speedup vs baseline: 1.0805x; 1.0805x over previous
//
#include <hip/hip_runtime.h>
#include <stdint.h>

// Problem constants: x[16,64,256,256] fp32, W[1024,1024] fp32, P=4.
// GEMM view: C[m,n] = sum_k A[m,k] * W[n,k]
//   m = b*4096 + hp*64 + wp   (Hp=Wp=64)
//   k = c*16 + ph*4 + pw
// Tiling: BM=128 (2 hp-rows x 64 wp), BN=128, BK=32 (2 channels), 32 K-iters.
//
// Round-3 structure (revert of round-2's A-direct experiment, which doubled
// L2 A-traffic and regressed): round-1 staging geometry, but BOTH tiles
// double-buffered in LDS -> ONE s_barrier per iteration with lgkm-only
// drain. Fragment reads of tile it come from the buffer written in the
// previous iteration; ds_writes of tile it+1 hide under MFMA; global
// prefetch runs 2 tiles ahead (a full body of slack).

typedef float    f32x4  __attribute__((ext_vector_type(4)));
typedef uint32_t u32x4  __attribute__((ext_vector_type(4)));
typedef __bf16   bf16x8 __attribute__((ext_vector_type(8)));

// Truncate two f32 to bf16 and pack into one u32 (lo in low half).
__device__ __forceinline__ uint32_t pack2(float lo, float hi) {
    return __builtin_amdgcn_perm(__builtin_bit_cast(uint32_t, hi),
                                 __builtin_bit_cast(uint32_t, lo),
                                 0x07060302u);
}

__global__ __launch_bounds__(256, 2)
void patchmix_kernel(const float* __restrict__ x,
                     const float* __restrict__ Wm,
                     float* __restrict__ y) {
    // ---- XCD-aware block swizzle (T1): contiguous M-chunk per XCD, N fastest.
    const int bx  = blockIdx.x;
    const int xcd = bx & 7;
    const int jj  = bx >> 3;       // 0..511 within this XCD
    const int nt  = jj & 7;        // N-tile fastest -> A-strip L2 reuse
    const int mt  = xcd * 64 + (jj >> 3);   // 0..511
    const int bb  = mt >> 5;       // batch 0..15
    const int hp0 = (mt & 31) << 1;// first of 2 hp rows
    const int n0  = nt << 7;

    const int t    = threadIdx.x;
    const int lane = t & 63;
    const int wave = t >> 6;
    const int wm   = wave >> 1;    // wave row in 2x2 grid
    const int wn   = wave & 1;     // wave col

    // Double-buffered bf16 tiles in MFMA-fragment order
    // [buf][kq(0..3)][rowS(0..127)] of u32x4 (8 KB per tile per buffer).
    // XOR skew (row ^ (kq<<1)) keeps writes/reads bank-conflict-free
    // (verified round 1: SQ_LDS_BANK_CONFLICT 2.5e7 -> 0).
    __shared__ u32x4 Alds[2][4 * 128];
    __shared__ u32x4 Blds[2][4 * 128];

    // ---- A staging geometry (per thread: 2 rounds x 2 rows x float4) ----
    // round r: rp = wave + 4r -> cL = r, hpL = (wave>>1)&1, phh = wave&1
    const int hpL = (wave >> 1) & 1;
    const int phh = wave & 1;
    const float* aBase0 = x + (size_t)bb * (64 * 256 * 256)
                            + ((size_t)(hp0 + hpL) * 4 + 2 * phh) * 256 + lane * 4;
    const int aM = hpL * 64 + lane;          // LDS row (= m_local)
    const int kqA0 = phh,     kqA1 = 2 + phh;
    const int aM0  = aM ^ (kqA0 << 1);
    const int aM1  = aM ^ (kqA1 << 1);

    // ---- B staging geometry ----
    const int bN  = t >> 2;                  // n_local 0..63 (round0), +64 (round1)
    const int bKq = t & 3;
    const int bNs = bN ^ (bKq << 1);         // skewed row
    const float* bBase0 = Wm + (size_t)(n0 + bN) * 1024 + bKq * 8;

    f32x4 aR[2][2], bR[2][2];

    auto loadAB = [&](int it) {
        const float* a0 = aBase0 + (size_t)(it * 2) * 65536;
        aR[0][0] = *(const f32x4*)(a0);
        aR[0][1] = *(const f32x4*)(a0 + 256);
        aR[1][0] = *(const f32x4*)(a0 + 65536);
        aR[1][1] = *(const f32x4*)(a0 + 65536 + 256);
        const float* b0 = bBase0 + it * 32;
        bR[0][0] = *(const f32x4*)(b0);
        bR[0][1] = *(const f32x4*)(b0 + 4);
        bR[1][0] = *(const f32x4*)(b0 + 65536);   // +64 rows * 1024
        bR[1][1] = *(const f32x4*)(b0 + 65536 + 4);
    };

    // pack currently staged regs -> bf16 and write into buffers (AW, BW)
    auto stageWrite = [&](u32x4* AW, u32x4* BW) {
        u32x4 apk0 = (u32x4){ pack2(aR[0][0].x, aR[0][0].y), pack2(aR[0][0].z, aR[0][0].w),
                              pack2(aR[0][1].x, aR[0][1].y), pack2(aR[0][1].z, aR[0][1].w) };
        u32x4 apk1 = (u32x4){ pack2(aR[1][0].x, aR[1][0].y), pack2(aR[1][0].z, aR[1][0].w),
                              pack2(aR[1][1].x, aR[1][1].y), pack2(aR[1][1].z, aR[1][1].w) };
        u32x4 bpk0 = (u32x4){ pack2(bR[0][0].x, bR[0][0].y), pack2(bR[0][0].z, bR[0][0].w),
                              pack2(bR[0][1].x, bR[0][1].y), pack2(bR[0][1].z, bR[0][1].w) };
        u32x4 bpk1 = (u32x4){ pack2(bR[1][0].x, bR[1][0].y), pack2(bR[1][0].z, bR[1][0].w),
                              pack2(bR[1][1].x, bR[1][1].y), pack2(bR[1][1].z, bR[1][1].w) };
        AW[kqA0 * 128 + aM0]      = apk0;
        AW[kqA1 * 128 + aM1]      = apk1;
        BW[bKq * 128 + bNs]       = bpk0;
        BW[bKq * 128 + 64 + bNs]  = bpk1;
    };

    f32x4 acc[4][4];
    #pragma unroll
    for (int i = 0; i < 4; ++i)
        #pragma unroll
        for (int j = 0; j < 4; ++j)
            acc[i][j] = (f32x4){0.f, 0.f, 0.f, 0.f};

    const int kg  = lane >> 4;   // k-group 0..3
    const int lr  = lane & 15;
    const int lrS = lr ^ (kg << 1);   // skewed fragment row

    // ---- prologue: tile 0 -> buf0, tile 1 staged in regs ----
    loadAB(0);
    stageWrite(&Alds[0][0], &Blds[0][0]);
    loadAB(1);
    asm volatile("s_waitcnt lgkmcnt(0)" ::: "memory");
    __builtin_amdgcn_s_barrier();
    asm volatile("" ::: "memory");

    // body(it): tile it readable in buf[it&1]; tile it+1 in staging regs.
    //   Reads tile it, packs+writes tile it+1 into buf[(it+1)&1],
    //   prefetches tile it+2, MFMAs, then lgkm-drain + barrier.
    // Safety: each wave's lgkmcnt(0) before the barrier drains its reads of
    // buf[it&1]; body(it+1) writes that buffer only after the barrier.
    auto body = [&](int it, const u32x4* AR, const u32x4* BR,
                    u32x4* AW, u32x4* BW, bool doLoad) {
        // 1. fragment reads of tile it (issued early; latency hidden by pack)
        bf16x8 af[4], bfr[4];
        #pragma unroll
        for (int i = 0; i < 4; ++i)
            af[i] = __builtin_bit_cast(bf16x8, AR[kg * 128 + wm * 64 + i * 16 + lrS]);
        #pragma unroll
        for (int j = 0; j < 4; ++j)
            bfr[j] = __builtin_bit_cast(bf16x8, BR[kg * 128 + wn * 64 + j * 16 + lrS]);
        // 2. pack tile it+1 and write into the other buffer (hides under MFMA)
        stageWrite(AW, BW);
        // 3. prefetch tile it+2 (full body of slack before its pack)
        if (doLoad) loadAB(it + 2);
        // 4. MFMA on tile it
        #pragma unroll
        for (int i = 0; i < 4; ++i)
            #pragma unroll
            for (int j = 0; j < 4; ++j)
                acc[i][j] = __builtin_amdgcn_mfma_f32_16x16x32_bf16(
                                af[i], bfr[j], acc[i][j], 0, 0, 0);
        // 5. lgkm-only drain + barrier (global prefetch stays in flight)
        asm volatile("s_waitcnt lgkmcnt(0)" ::: "memory");
        __builtin_amdgcn_s_barrier();
        asm volatile("" ::: "memory");
    };

    #pragma unroll 1
    for (int it2 = 0; it2 < 15; ++it2) {
        body(2 * it2,     &Alds[0][0], &Blds[0][0], &Alds[1][0], &Blds[1][0], true);
        body(2 * it2 + 1, &Alds[1][0], &Blds[1][0], &Alds[0][0], &Blds[0][0], true);
    }
    body(30, &Alds[0][0], &Blds[0][0], &Alds[1][0], &Blds[1][0], false);
    // tail: tile 31 from buf1, no write/load/barrier
    {
        bf16x8 af[4], bfr[4];
        #pragma unroll
        for (int i = 0; i < 4; ++i)
            af[i] = __builtin_bit_cast(bf16x8, Alds[1][kg * 128 + wm * 64 + i * 16 + lrS]);
        #pragma unroll
        for (int j = 0; j < 4; ++j)
            bfr[j] = __builtin_bit_cast(bf16x8, Blds[1][kg * 128 + wn * 64 + j * 16 + lrS]);
        #pragma unroll
        for (int i = 0; i < 4; ++i)
            #pragma unroll
            for (int j = 0; j < 4; ++j)
                acc[i][j] = __builtin_amdgcn_mfma_f32_16x16x32_bf16(
                                af[i], bfr[j], acc[i][j], 0, 0, 0);
    }

    // ---- epilogue: fold back to y[b][c][h][w] ----
    // D layout (m89): col n = lane&15, row m = (lane>>4)*4 + reg
    // m_local = wm*64 + i*16 + kg*4 + r  ->  hpL = wm, wp = i*16 + kg*4 + r
    float* yb = y + (size_t)bb * (64 * 256 * 256)
                  + ((size_t)(hp0 + wm) * 4) * 256;
    #pragma unroll
    for (int j = 0; j < 4; ++j) {
        const int ng = n0 + wn * 64 + j * 16 + lr;   // output channel-dim index e
        const int cc = ng >> 4;
        const int ph = (ng >> 2) & 3;
        const int pw = ng & 3;
        float* ybase = yb + ((size_t)cc * 256 + ph) * 256 + pw;
        #pragma unroll
        for (int i = 0; i < 4; ++i) {
            const int wpB = i * 16 + kg * 4;
            #pragma unroll
            for (int r = 0; r < 4; ++r)
                ybase[(size_t)(wpB + r) * 4] = acc[i][j][r];
        }
    }
}

extern "C" void kernel_launch(void* const* d_in, const int* in_sizes, int n_in,
                              void* d_out, int out_size, void* d_ws, size_t ws_size,
                              hipStream_t stream) {
    (void)in_sizes; (void)n_in; (void)d_ws; (void)ws_size; (void)out_size;
    const float* x  = (const float*)d_in[0];
    const float* Wm = (const float*)d_in[1];
    float* y = (float*)d_out;
    // 512 M-tiles x 8 N-tiles, XCD-swizzled inside the kernel
    patchmix_kernel<<<dim3(4096), dim3(256), 0, stream>>>(x, Wm, y);
}

// Round 5
// 622.150 us; speedup vs baseline: 1.1570x; 1.0709x over previous
//
#include <hip/hip_runtime.h>
#include <stdint.h>

// Problem constants: x[16,64,256,256] fp32, W[1024,1024] fp32, P=4.
// GEMM view: C[m,n] = sum_k A[m,k] * W[n,k]
//   m = b*4096 + hp*64 + wp   (Hp=Wp=64)
//   k = c*16 + ph*4 + pw
// Tiling: BM=128 (2 hp-rows x 64 wp), BN=128, BK=32 (2 channels), 32 K-iters.
//
// Structure: round-1 skeleton for A (LDS-staged, XOR-skewed, 2 barriers/iter,
// single 8 KB buffer — verified best at 322 µs), but B comes from a
// pre-converted bf16 fragment-ordered table Wp[kq][n] (2 MB, L2-resident)
// built once per call in d_ws by a tiny prep kernel. B fragments are then a
// single global_load_dwordx4 per lane: no pack, no LDS, no barrier
// dependency. Barriers are raw s_barrier + lgkm-only drain so the A global
// prefetch (issued before bar1) stays in flight across both barriers.

typedef float    f32x4  __attribute__((ext_vector_type(4)));
typedef uint32_t u32x4  __attribute__((ext_vector_type(4)));
typedef __bf16   bf16x8 __attribute__((ext_vector_type(8)));

// Truncate two f32 to bf16 and pack into one u32 (lo in low half).
__device__ __forceinline__ uint32_t pack2(float lo, float hi) {
    return __builtin_amdgcn_perm(__builtin_bit_cast(uint32_t, hi),
                                 __builtin_bit_cast(uint32_t, lo),
                                 0x07060302u);
}

// ---- W prep: W[n][k] fp32 -> Wp granule[kq][n] = 8 bf16 {k=kq*8..kq*8+7} ----
// 128k granules total (kq 0..127, n 0..1023) = 2 MB.
__global__ __launch_bounds__(256)
void wprep_kernel(const float* __restrict__ Wm, u32x4* __restrict__ Wp) {
    const int t  = blockIdx.x * 256 + threadIdx.x;   // 0..131071
    if (t >= 128 * 1024) return;
    const int n  = t & 1023;                          // write-coalesced in n
    const int kq = t >> 10;                           // 0..127
    const float* src = Wm + (size_t)n * 1024 + (size_t)kq * 8;
    f32x4 lo = *(const f32x4*)(src);
    f32x4 hi = *(const f32x4*)(src + 4);
    Wp[(size_t)kq * 1024 + n] = (u32x4){ pack2(lo.x, lo.y), pack2(lo.z, lo.w),
                                         pack2(hi.x, hi.y), pack2(hi.z, hi.w) };
}

__global__ __launch_bounds__(256, 2)
void patchmix_kernel(const float* __restrict__ x,
                     const u32x4* __restrict__ Wp,
                     float* __restrict__ y) {
    // ---- XCD-aware block swizzle (T1): contiguous M-chunk per XCD, N fastest.
    const int bx  = blockIdx.x;
    const int xcd = bx & 7;
    const int jj  = bx >> 3;       // 0..511 within this XCD
    const int nt  = jj & 7;        // N-tile fastest -> A-strip L2 reuse
    const int mt  = xcd * 64 + (jj >> 3);   // 0..511
    const int bb  = mt >> 5;       // batch 0..15
    const int hp0 = (mt & 31) << 1;// first of 2 hp rows
    const int n0  = nt << 7;

    const int t    = threadIdx.x;
    const int lane = t & 63;
    const int wave = t >> 6;
    const int wm   = wave >> 1;    // wave row in 2x2 grid
    const int wn   = wave & 1;     // wave col

    // A tile only: [kq(0..3)][rowS(0..127)] of u32x4 = 8 KB single buffer.
    // XOR skew (row ^ (kq<<1)): bank-conflict-free (round-1 verified: 0).
    __shared__ u32x4 Alds[4 * 128];

    // ---- A staging geometry (round-1 verbatim) ----
    const int hpL = (wave >> 1) & 1;
    const int phh = wave & 1;
    const float* aBase0 = x + (size_t)bb * (64 * 256 * 256)
                            + ((size_t)(hp0 + hpL) * 4 + 2 * phh) * 256 + lane * 4;
    const int aM = hpL * 64 + lane;          // LDS row (= m_local)
    const int kqA0 = phh,     kqA1 = 2 + phh;
    const int aM0  = aM ^ (kqA0 << 1);
    const int aM1  = aM ^ (kqA1 << 1);

    const int kg  = lane >> 4;   // k-group 0..3
    const int lr  = lane & 15;
    const int lrS = lr ^ (kg << 1);

    // B fragment pointer: granule (it*4+kg)*1024 + (n0 + wn*64 + j*16 + lr)
    const u32x4* bFrag = Wp + (size_t)kg * 1024 + (size_t)(n0 + wn * 64 + lr);

    f32x4 aR[2][2];
    auto loadA = [&](int it) {
        const float* a0 = aBase0 + (size_t)(it * 2) * 65536;
        aR[0][0] = *(const f32x4*)(a0);
        aR[0][1] = *(const f32x4*)(a0 + 256);
        aR[1][0] = *(const f32x4*)(a0 + 65536);
        aR[1][1] = *(const f32x4*)(a0 + 65536 + 256);
    };

    f32x4 acc[4][4];
    #pragma unroll
    for (int i = 0; i < 4; ++i)
        #pragma unroll
        for (int j = 0; j < 4; ++j)
            acc[i][j] = (f32x4){0.f, 0.f, 0.f, 0.f};

    loadA(0);

    #pragma unroll 1
    for (int it = 0; it < 32; ++it) {
        // 1. pack A(it) -> bf16 (waits on aR loads; slack = full prev iter)
        u32x4 apk0 = (u32x4){ pack2(aR[0][0].x, aR[0][0].y), pack2(aR[0][0].z, aR[0][0].w),
                              pack2(aR[0][1].x, aR[0][1].y), pack2(aR[0][1].z, aR[0][1].w) };
        u32x4 apk1 = (u32x4){ pack2(aR[1][0].x, aR[1][0].y), pack2(aR[1][0].z, aR[1][0].w),
                              pack2(aR[1][1].x, aR[1][1].y), pack2(aR[1][1].z, aR[1][1].w) };
        // 2. issue B fragments for this iter (bf16, L2-resident, no pack)
        bf16x8 bfr[4];
        {
            const u32x4* bi = bFrag + (size_t)it * 4096;
            #pragma unroll
            for (int j = 0; j < 4; ++j)
                bfr[j] = __builtin_bit_cast(bf16x8, bi[j * 16]);
        }
        // 3. prefetch A(it+1): stays in flight across both barriers
        if (it + 1 < 32) loadA(it + 1);
        // 4. bar1: all waves done reading Alds tile it-1 (lgkm-only drain;
        //    global prefetch NOT drained — that's the point of raw barriers)
        asm volatile("s_waitcnt lgkmcnt(0)" ::: "memory");
        __builtin_amdgcn_s_barrier();
        asm volatile("" ::: "memory");
        // 5. write A(it)
        Alds[kqA0 * 128 + aM0] = apk0;
        Alds[kqA1 * 128 + aM1] = apk1;
        // 6. bar2: tile it visible
        asm volatile("s_waitcnt lgkmcnt(0)" ::: "memory");
        __builtin_amdgcn_s_barrier();
        asm volatile("" ::: "memory");
        // 7. read A fragments + MFMA
        bf16x8 af[4];
        #pragma unroll
        for (int i = 0; i < 4; ++i)
            af[i] = __builtin_bit_cast(bf16x8, Alds[kg * 128 + wm * 64 + i * 16 + lrS]);
        #pragma unroll
        for (int i = 0; i < 4; ++i)
            #pragma unroll
            for (int j = 0; j < 4; ++j)
                acc[i][j] = __builtin_amdgcn_mfma_f32_16x16x32_bf16(
                                af[i], bfr[j], acc[i][j], 0, 0, 0);
    }

    // ---- epilogue: fold back to y[b][c][h][w] (round-1 verbatim) ----
    // D layout (m89): col n = lane&15, row m = (lane>>4)*4 + reg
    // m_local = wm*64 + i*16 + kg*4 + r  ->  hpL = wm, wp = i*16 + kg*4 + r
    float* yb = y + (size_t)bb * (64 * 256 * 256)
                  + ((size_t)(hp0 + wm) * 4) * 256;
    #pragma unroll
    for (int j = 0; j < 4; ++j) {
        const int ng = n0 + wn * 64 + j * 16 + lr;   // output channel-dim index e
        const int cc = ng >> 4;
        const int ph = (ng >> 2) & 3;
        const int pw = ng & 3;
        float* ybase = yb + ((size_t)cc * 256 + ph) * 256 + pw;
        #pragma unroll
        for (int i = 0; i < 4; ++i) {
            const int wpB = i * 16 + kg * 4;
            #pragma unroll
            for (int r = 0; r < 4; ++r)
                ybase[(size_t)(wpB + r) * 4] = acc[i][j][r];
        }
    }
}

extern "C" void kernel_launch(void* const* d_in, const int* in_sizes, int n_in,
                              void* d_out, int out_size, void* d_ws, size_t ws_size,
                              hipStream_t stream) {
    (void)in_sizes; (void)n_in; (void)out_size; (void)ws_size;
    const float* x  = (const float*)d_in[0];
    const float* Wm = (const float*)d_in[1];
    float* y = (float*)d_out;
    u32x4* Wp = (u32x4*)d_ws;   // needs 2 MB; harness workspace is larger
    wprep_kernel<<<dim3(512), dim3(256), 0, stream>>>(Wm, Wp);
    patchmix_kernel<<<dim3(4096), dim3(256), 0, stream>>>(x, Wp, y);
}